// Round 6
// baseline (460.388 us; speedup 1.0000x reference)
//
#include <hip/hip_runtime.h>
#include <math.h>

typedef long long i64;
typedef __attribute__((ext_vector_type(8))) short bf16x8;
typedef __attribute__((ext_vector_type(4))) float f32x4;

#define TEMP_ISQ 0.047245559f   // 1/sqrt(448)

__device__ __forceinline__ unsigned short f2b(float x) {
  union { float f; unsigned u; } a; a.f = x;
  return (unsigned short)((a.u + 0x7fffu + ((a.u >> 16) & 1u)) >> 16);
}
__device__ __forceinline__ float b2f(unsigned short b) {
  union { float f; unsigned u; } a; a.u = ((unsigned)b) << 16; return a.f;
}

// ================= NT bf16 MFMA GEMM =================
// out[M,N] = A[M,K] @ BT[N,K]^T (+bias). 128x128 tile, BK=32 double-buffered
// (prefetch next K-tile before computing current -> loads fly under MFMA,
// ONE barrier per K-step). T1 chunked XCD swizzle (requires nwg % 8 == 0).
// BIAS: 0 none, 1 col bias[col], 2 row bias[row]
// OUTM: 0 fp32, 1 bf16, 2 both (fp32 Ob + bf16 O2b), 3 fp32 tanh(acc/3)
// RS:   1 -> v *= tanhf(rowScale[z*sRS + row] + rsAdd[z])
// BZDIV: B batch index = z / BZDIV
// XMODE: 1 -> G8 mode: z' -> (b=z'/3, i=z'%3); A/B offset doffs[i], Kd from table
template<int BIAS, int OUTM, int RS, int BZDIV, int XMODE = 0>
__global__ __launch_bounds__(256)
void gemm_mfma(const unsigned short* __restrict__ Ab, i64 sA,
               const unsigned short* __restrict__ Bb, i64 sB,
               const float* __restrict__ bias,
               void* __restrict__ Ob, i64 sO,
               unsigned short* __restrict__ O2b, i64 sO2,
               int Nn, int Kd, int ldA, int ldB, int ldO,
               const float* __restrict__ rowScale, i64 sRS,
               const float* __restrict__ rsAdd)
{
  __shared__ unsigned short As[2][4096];   // 2 x (128 rows x 32 cols) bf16 = 16KB
  __shared__ unsigned short Bs[2][4096];
  const int tid = threadIdx.x;
  const int w = tid >> 6, lane = tid & 63;

  // T1 chunked XCD swizzle
  const int gx = gridDim.x, gy = gridDim.y;
  int nwg = gx * gy * gridDim.z;
  int bid = blockIdx.x + gx * (blockIdx.y + gy * blockIdx.z);
  int L = bid;
  if ((nwg & 7) == 0) L = (bid & 7) * (nwg >> 3) + (bid >> 3);
  const int bx = L % gx;
  int rem = L / gx;
  const int by = rem % gy;
  const int z  = rem / gy;

  const int m0 = by * 128, n0 = bx * 128;
  const unsigned short* A;
  const unsigned short* B;
  int KdL = Kd;
  if (XMODE == 1) {
    int bb = z / 3, ii = z - bb * 3;
    const int dof_[3] = {0, 256, 384};
    const int kdt_[3] = {256, 128, 64};
    A = Ab + dof_[ii] + (i64)bb * sA;
    B = Bb + dof_[ii] + (i64)bb * sB;
    KdL = kdt_[ii];
  } else {
    A = Ab + (i64)z * sA;
    B = Bb + (i64)(BZDIV == 1 ? z : z / BZDIV) * sB;
  }
  const int wr = w >> 1, wc = w & 1;
  const int rS = tid >> 2, sS = tid & 3;       // stage: row (0..63), slot (0..3)
  const int cL = lane & 15, sl = lane >> 4;

  f32x4 acc[4][4];
  #pragma unroll
  for (int i = 0; i < 4; ++i)
    #pragma unroll
    for (int j = 0; j < 4; ++j) acc[i][j] = (f32x4){0.f, 0.f, 0.f, 0.f};

  // stage one 128x32 K-tile into buffer `buf` from column k0.
  // LDS dest linear (tid*16 B per issue); source slot pre-XOR'd (rule #21).
  auto STAGE = [&](int buf, int k0) {
    #pragma unroll
    for (int q = 0; q < 2; ++q) {
      int r = rS + q * 64;
      int sg = sS ^ (r & 3);
      const unsigned short* sa = A + (i64)(m0 + r) * ldA + k0 + sg * 8;
      const unsigned short* sb = B + (i64)(n0 + r) * ldB + k0 + sg * 8;
      __builtin_amdgcn_global_load_lds(
          (__attribute__((address_space(1))) void*)sa,
          (__attribute__((address_space(3))) void*)&As[buf][r * 32 + sS * 8], 16, 0, 0);
      __builtin_amdgcn_global_load_lds(
          (__attribute__((address_space(1))) void*)sb,
          (__attribute__((address_space(3))) void*)&Bs[buf][r * 32 + sS * 8], 16, 0, 0);
    }
  };

  STAGE(0, 0);
  __syncthreads();

  for (int k0 = 0; k0 < KdL; k0 += 32) {
    const int cur = (k0 >> 5) & 1;
    if (k0 + 32 < KdL) STAGE(cur ^ 1, k0 + 32);   // prefetch flies under compute
    bf16x8 af[4], bfv[4];
    #pragma unroll
    for (int mi = 0; mi < 4; ++mi) {
      int rr = wr * 64 + mi * 16 + cL;
      int ph = sl ^ (rr & 3);
      af[mi] = *(const bf16x8*)&As[cur][rr * 32 + ph * 8];
    }
    #pragma unroll
    for (int ni = 0; ni < 4; ++ni) {
      int rr = wc * 64 + ni * 16 + cL;
      int ph = sl ^ (rr & 3);
      bfv[ni] = *(const bf16x8*)&Bs[cur][rr * 32 + ph * 8];
    }
    #pragma unroll
    for (int mi = 0; mi < 4; ++mi)
      #pragma unroll
      for (int ni = 0; ni < 4; ++ni)
        acc[mi][ni] = __builtin_amdgcn_mfma_f32_16x16x32_bf16(af[mi], bfv[ni], acc[mi][ni], 0, 0, 0);
    __syncthreads();   // drains prefetch (had full compute phase in flight) + protects buffers
  }

  // D layout: col=lane&15, row=(lane>>4)*4+reg
  #pragma unroll
  for (int mi = 0; mi < 4; ++mi) {
    const int rowb = m0 + wr * 64 + mi * 16 + sl * 4;
    #pragma unroll
    for (int ni = 0; ni < 4; ++ni) {
      const int col = n0 + wc * 64 + ni * 16 + cL;
      if (col < Nn) {
        float bc = (BIAS == 1) ? bias[col] : 0.f;
        #pragma unroll
        for (int rg = 0; rg < 4; ++rg) {
          float v = acc[mi][ni][rg];
          if (RS) v *= tanhf(rowScale[(i64)z * sRS + rowb + rg] + rsAdd[z]);
          v += bc;
          if (BIAS == 2) v += bias[rowb + rg];
          i64 oidx = (i64)(rowb + rg) * ldO + col;
          if (OUTM == 0)      ((float*)Ob)[(i64)z * sO + oidx] = v;
          else if (OUTM == 1) ((unsigned short*)Ob)[(i64)z * sO + oidx] = f2b(v);
          else if (OUTM == 3) ((float*)Ob)[(i64)z * sO + oidx] = tanhf(v * (1.f / 3.f));
          else {
            ((float*)Ob)[(i64)z * sO + oidx] = v;
            O2b[(i64)z * sO2 + oidx] = f2b(v);
          }
        }
      }
    }
  }
}

// ================= fused emo pass =================
// 2048 blocks (16 rows each): colPart [32][64][1024], dotE, emoB
__global__ __launch_bounds__(256)
void emo_pass1(const float* __restrict__ emo, const float* __restrict__ eleW,
               unsigned short* __restrict__ emoB, float* __restrict__ colPart,
               float* __restrict__ dotE) {
  int b = blockIdx.y, lc = blockIdx.x;   // 64 chunks x 16 rows
  int t = threadIdx.x, lane = t & 63, w = t >> 6;
  float4 w4 = ((const float4*)eleW)[t];
  float4 acc = make_float4(0.f, 0.f, 0.f, 0.f);
  __shared__ float dw[16][4];
  const float4* src = (const float4*)emo + ((i64)b * 1024 + lc * 16) * 256;
  ushort4* dst = (ushort4*)emoB + ((i64)b * 1024 + lc * 16) * 256;
  #pragma unroll 4
  for (int lr = 0; lr < 16; ++lr) {
    float4 v = src[lr * 256 + t];
    acc.x += v.x; acc.y += v.y; acc.z += v.z; acc.w += v.w;
    float d = v.x * w4.x + v.y * w4.y + v.z * w4.z + v.w * w4.w;
    #pragma unroll
    for (int o = 32; o; o >>= 1) d += __shfl_xor(d, o);
    if (!lane) dw[lr][w] = d;
    ushort4 o4; o4.x = f2b(v.x); o4.y = f2b(v.y); o4.z = f2b(v.z); o4.w = f2b(v.w);
    dst[lr * 256 + t] = o4;
  }
  __syncthreads();
  if (t < 16) dotE[(i64)b * 1024 + lc * 16 + t] = dw[t][0] + dw[t][1] + dw[t][2] + dw[t][3];
  ((float4*)colPart)[((i64)b * 64 + lc) * 256 + t] = acc;
}

__global__ void colmean2(const float* __restrict__ colPart, float* __restrict__ emomean) {
  int b = blockIdx.y, e = blockIdx.x * 256 + threadIdx.x;
  float s = 0.f;
  #pragma unroll 8
  for (int lc = 0; lc < 64; ++lc) s += colPart[((i64)b * 64 + lc) * 1024 + e];
  emomean[b * 1024 + e] = s * (1.f / 1024.f);
}

// ================= prep kernels =================
// all 7 weight transposes in one launch. grid (101, 32).
__global__ __launch_bounds__(256)
void transpose_all(const float* __restrict__ w_v_W, const float* __restrict__ agg_a_W,
                   const float* __restrict__ agg_c_W, const float* __restrict__ wq_W,
                   const float* __restrict__ wk_W, const float* __restrict__ wv_W,
                   const float* __restrict__ wr_W,
                   unsigned short* __restrict__ wvT, unsigned short* __restrict__ aaT,
                   unsigned short* __restrict__ acT, unsigned short* __restrict__ wqT,
                   unsigned short* __restrict__ kvrT) {
  __shared__ float T[32][33];
  int bx = blockIdx.x;
  const float* in; unsigned short* out; int N, Npad, s0;
  if (bx < 32)      { in = w_v_W;   out = wvT;                     N = 1024; Npad = 1024; s0 = 0; }
  else if (bx < 36) { in = agg_a_W; out = aaT;                     N = 128;  Npad = 128;  s0 = 32; }
  else if (bx < 68) { in = agg_c_W; out = acT;                     N = 1024; Npad = 1024; s0 = 36; }
  else if (bx < 84) { in = wq_W;    out = wqT;                     N = 448;  Npad = 512;  s0 = 68; }
  else if (bx < 98) { in = wk_W;    out = kvrT;                    N = 448;  Npad = 448;  s0 = 84; }
  else if (bx < 99) { in = wv_W;    out = kvrT + (i64)448 * 1024;  N = 28;   Npad = 28;   s0 = 98; }
  else              { in = wr_W;    out = kvrT + (i64)476 * 1024;  N = 3;    Npad = 36;   s0 = 99; }
  int n0 = (bx - s0) * 32, k0 = blockIdx.y * 32;
  int t = threadIdx.x;
  #pragma unroll
  for (int p = 0; p < 4; ++p) {
    int idx = t + 256 * p; int kk = idx >> 5, nn = idx & 31;
    float v = 0.f;
    if (n0 + nn < N) v = in[(i64)(k0 + kk) * N + (n0 + nn)];
    T[nn][kk] = v;
  }
  __syncthreads();
  #pragma unroll
  for (int p = 0; p < 4; ++p) {
    int idx = t + 256 * p; int nn = idx >> 5, kk = idx & 31;
    if (n0 + nn < Npad) out[(i64)(n0 + nn) * 1024 + (k0 + kk)] = f2b(T[nn][kk]);
  }
}

__global__ void kvr_bias_kernel(const float* wkb, const float* wvb, const float* wrb, float* out) {
  int t = blockIdx.x * 256 + threadIdx.x;
  if (t >= 480) return;
  out[t] = (t < 448) ? wkb[t] : (t < 476) ? wvb[t - 448] : (t < 479) ? wrb[t - 476] : 0.f;
}

__global__ void pool_phr(const float* __restrict__ phr, unsigned short* __restrict__ out) {
  i64 idx = (i64)blockIdx.x * 256 + threadIdx.x;
  if (idx >= 2097152) return;
  i64 bm = idx >> 8; int c = (int)(idx & 255);
  i64 b = bm >> 8, m = bm & 255;
  const float4* r0 = (const float4*)(phr + (b * 512 + 2 * m) * 1024) + c;
  const float4* r1 = (const float4*)(phr + (b * 512 + 2 * m + 1) * 1024) + c;
  float4 a = *r0, d = *r1;
  ushort4 o;
  o.x = f2b(0.5f * (a.x + d.x)); o.y = f2b(0.5f * (a.y + d.y));
  o.z = f2b(0.5f * (a.z + d.z)); o.w = f2b(0.5f * (a.w + d.w));
  ((ushort4*)out)[idx] = o;
}

__global__ void vconv(const float* __restrict__ video, unsigned short* __restrict__ combine) {
  i64 idx = (i64)blockIdx.x * 256 + threadIdx.x;
  if (idx >= 2097152) return;
  i64 b = idx >> 16, r = idx & 65535;
  float4 v = ((const float4*)video)[idx];
  ushort4 o;
  o.x = f2b(v.x); o.y = f2b(v.y); o.z = f2b(v.z); o.w = f2b(v.w);
  ((ushort4*)combine)[b * 131072 + 65536 + r] = o;
}

// VT[b][n][k] = KVR[b][k][448+n] (n<28), 0 pad to 128 rows
__global__ void vt_fill(const unsigned short* __restrict__ KVR, unsigned short* __restrict__ VT) {
  int b = blockIdx.y;
  int idx = blockIdx.x * 256 + threadIdx.x;
  int n = idx >> 7, k = idx & 127;
  unsigned short v = 0;
  if (n < 28) v = KVR[(i64)b * 61440 + k * 480 + 448 + n];
  VT[((i64)b * 128 + n) * 128 + k] = v;
}

// ================= softmax / routing =================
__global__ void softmax_attn_a(const float* __restrict__ logits, unsigned short* __restrict__ outT) {
  int gw = (int)(((i64)blockIdx.x * blockDim.x + threadIdx.x) >> 6);
  int lane = threadIdx.x & 63;
  if (gw >= 32 * 512) return;
  int b = gw >> 9, m = gw & 511;
  const float* p = logits + (i64)gw * 128;
  float x0 = p[lane], x1 = p[lane + 64];
  float mx = fmaxf(x0, x1);
  #pragma unroll
  for (int o = 32; o; o >>= 1) mx = fmaxf(mx, __shfl_xor(mx, o));
  float e0 = expf(x0 - mx), e1 = expf(x1 - mx);
  float s = e0 + e1;
  #pragma unroll
  for (int o = 32; o; o >>= 1) s += __shfl_xor(s, o);
  float inv = 1.f / s;
  unsigned short* o0 = outT + (i64)b * 128 * 512 + m;
  o0[(i64)lane * 512] = f2b(e0 * inv);
  o0[(i64)(lane + 64) * 512] = f2b(e1 * inv);
}

// in-place: each warp owns one row of PL; reads fully before writing
__global__ void softmax_P_bf(const unsigned short* __restrict__ PL, unsigned short* __restrict__ P) {
  i64 gw = ((i64)blockIdx.x * blockDim.x + threadIdx.x) >> 6;
  int lane = threadIdx.x & 63;
  if (gw >= 98304) return;
  const unsigned short* p = PL + gw * 128;
  float x0 = b2f(p[lane]) * TEMP_ISQ, x1 = b2f(p[lane + 64]) * TEMP_ISQ;
  float mx = fmaxf(x0, x1);
  #pragma unroll
  for (int o = 32; o; o >>= 1) mx = fmaxf(mx, __shfl_xor(mx, o));
  float e0 = expf(x0 - mx), e1 = expf(x1 - mx);
  float s = e0 + e1;
  #pragma unroll
  for (int o = 32; o; o >>= 1) s += __shfl_xor(s, o);
  float inv = 1.f / s;
  P[gw * 128 + lane] = f2b(e0 * inv);
  P[gw * 128 + lane + 64] = f2b(e1 * inv);
}

__global__ void apool_kernel(const float* __restrict__ emomean, const float* __restrict__ agg,
                             float* __restrict__ Apool) {
  int gw = (int)(((i64)blockIdx.x * blockDim.x + threadIdx.x) >> 6);
  int lane = threadIdx.x & 63;
  if (gw >= 32 * 128) return;
  int b = gw >> 7, k = gw & 127;
  const float* ag = agg + ((i64)b * 128 + k) * 1024;
  const float* em = emomean + (i64)b * 1024;
  float s = 0.f;
  #pragma unroll
  for (int j = 0; j < 16; ++j) { int e = j * 64 + lane; s += em[e] * ag[e]; }
  #pragma unroll
  for (int o = 32; o; o >>= 1) s += __shfl_down(s, o);
  if (!lane) Apool[gw] = s;
}

// route[b,e] = sum_k Apool[b,k]*agg[b,k,e]  (grid (4,32))
__global__ void route_kernel(const float* __restrict__ Apool, const float* __restrict__ agg,
                             float* __restrict__ route) {
  int b = blockIdx.y;
  int e = blockIdx.x * 256 + threadIdx.x;
  __shared__ float Ap[128];
  if (threadIdx.x < 128) Ap[threadIdx.x] = Apool[b * 128 + threadIdx.x];
  __syncthreads();
  const float* ag = agg + (i64)b * 128 * 1024 + e;
  float s = 0.f;
  #pragma unroll 8
  for (int k = 0; k < 128; ++k) s += Ap[k] * ag[(i64)k * 1024];
  route[b * 1024 + e] = s;
}

__global__ void rb_kernel(const float* __restrict__ route, const float* __restrict__ eleW,
                          const float* __restrict__ eleb, float* __restrict__ rb) {
  int b = blockIdx.x, t = threadIdx.x;
  float s = 0.f;
  for (int j = t; j < 1024; j += 256) s += route[b * 1024 + j] * eleW[1024 + j];
  __shared__ float red[256];
  red[t] = s; __syncthreads();
  for (int o = 128; o > 0; o >>= 1) { if (t < o) red[t] += red[t + o]; __syncthreads(); }
  if (t == 0) rb[b] = red[0] + eleb[0];
}

// ================= P consumers =================
__global__ void pmean1_kernel(const unsigned short* __restrict__ P, float* __restrict__ Ppart) {
  int bi = blockIdx.x, c = blockIdx.y, k = threadIdx.x;
  const unsigned short* p = P + ((i64)bi * 1024 + c * 128) * 128 + k;
  float s = 0.f;
  for (int l = 0; l < 128; ++l) s += b2f(p[(i64)l * 128]);
  Ppart[((i64)bi * 8 + c) * 128 + k] = s;
}

// fused pmean2 + rdiag + gate (32 blocks x 128 threads)
__global__ void pmean2_rdiag(const float* __restrict__ Ppart, const unsigned short* __restrict__ KVR,
                             float* __restrict__ gate) {
  int b = blockIdx.x, t = threadIdx.x;
  __shared__ float red[128];
  __shared__ float rd[3];
  for (int i = 0; i < 3; ++i) {
    float s = 0.f;
    #pragma unroll
    for (int c = 0; c < 8; ++c) s += Ppart[((i64)(b * 3 + i) * 8 + c) * 128 + t];
    float v = s * (1.f / 1024.f) * b2f(KVR[(i64)b * 61440 + t * 480 + 476 + i]);
    red[t] = v; __syncthreads();
    for (int o = 64; o > 0; o >>= 1) { if (t < o) red[t] += red[t + o]; __syncthreads(); }
    if (t == 0) rd[i] = red[0];
    __syncthreads();
  }
  if (t == 0) {
    float m = fmaxf(rd[0], fmaxf(rd[1], rd[2]));
    float e0 = expf(rd[0] - m), e1 = expf(rd[1] - m), e2 = expf(rd[2] - m);
    float inv = 1.f / (e0 + e1 + e2);
    gate[b * 3 + 0] = e0 * inv; gate[b * 3 + 1] = e1 * inv; gate[b * 3 + 2] = e2 * inv;
  }
}

// out = b2f(emoB) * (1 + tanh(dotE+rb) * sum_i gate_i * O_i)
__global__ __launch_bounds__(256)
void final_kernel(const unsigned short* __restrict__ emoB, const float* __restrict__ dotE,
                  const float* __restrict__ rbv, const float* __restrict__ O,
                  const float* __restrict__ gate, float* __restrict__ out) {
  i64 bl = blockIdx.x;
  int b = (int)(bl >> 10), l = (int)(bl & 1023);
  __shared__ float Gg[16];
  int t = threadIdx.x;
  if (t < 16) {
    float g0 = gate[b * 3], g1 = gate[b * 3 + 1], g2 = gate[b * 3 + 2];
    float o0 = O[((i64)(b * 3 + 0) * 1024 + l) * 28 + (t >> 2)];
    float o1 = O[((i64)(b * 3 + 1) * 1024 + l) * 28 + 4 + (t >> 1)];
    float o2 = O[((i64)(b * 3 + 2) * 1024 + l) * 28 + 12 + t];
    Gg[t] = g0 * o0 + g1 * o1 + g2 * o2;
  }
  __syncthreads();
  float re = tanhf(dotE[bl] + rbv[b]);
  ushort4 e4 = ((const ushort4*)(emoB + bl * 1024))[t];
  float g = 1.f + re * Gg[t >> 4];
  ((float4*)(out + bl * 1024))[t] =
      make_float4(b2f(e4.x) * g, b2f(e4.y) * g, b2f(e4.z) * g, b2f(e4.w) * g);
}

// ================= launcher =================
extern "C" void kernel_launch(void* const* d_in, const int* in_sizes, int n_in,
                              void* d_out, int out_size, void* d_ws, size_t ws_size,
                              hipStream_t stream) {
  const float* emo     = (const float*)d_in[0];
  const float* phr     = (const float*)d_in[1];
  const float* video   = (const float*)d_in[2];
  const float* w_v_W   = (const float*)d_in[3];
  const float* w_v_b   = (const float*)d_in[4];
  const float* agg_a_W = (const float*)d_in[5];
  const float* agg_a_b = (const float*)d_in[6];
  const float* agg_c_W = (const float*)d_in[7];
  const float* agg_c_b = (const float*)d_in[8];
  const float* ele_W   = (const float*)d_in[9];
  const float* ele_b   = (const float*)d_in[10];
  const float* wq_W    = (const float*)d_in[11];
  const float* wq_b    = (const float*)d_in[12];
  const float* wk_W    = (const float*)d_in[13];
  const float* wk_b    = (const float*)d_in[14];
  const float* wv_W    = (const float*)d_in[15];
  const float* wv_b    = (const float*)d_in[16];
  const float* wr_W    = (const float*)d_in[17];
  const float* wr_b    = (const float*)d_in[18];

  char* ws = (char*)d_ws;
  // ---- region map (bytes) ----
  const i64 oEmoB    = 0;            // ushort [32,1024,1024] 67,108,864 (live to the end)
  const i64 oCombine = 67108864;     // ushort [32,512,1024] (dead after G3')
  const i64 oPL      = 67108864;     //   overlay: ushort [96,1024,128]; softmax IN-PLACE -> P
  const i64 oPooled  = 100663296;    // ushort [32,256,1024] (dead after G1)
  const i64 oLogitsA = 100663296;    //   overlay: float [32,512,128] (dead after softmax_attn_a)
  const i64 oAggF    = 100663296;    //   overlay: float [32,128,1024] (dead after route)
  const i64 oO       = 100663296;    //   overlay: float [96,1024,28] (written after route)
  const i64 oCT      = 117440512;    // ushort [32,1024,512] (dead after G4)
  const i64 oQ       = 117440512;    //   overlay: ushort [32,1024,448]
  const i64 oAttnAT  = 150994944;    // ushort [32,128,512] 4,194,304
  const i64 oAggB    = 155189248;    // ushort [32,128,1024] 8,388,608
  const i64 oWvT     = 163577856;    // 2,097,152
  const i64 oAaT     = 165675008;    // 262,144
  const i64 oAcT     = 165937152;    // 2,097,152
  const i64 oWqT     = 168034304;    // 1,048,576
  const i64 oKvrT    = 169082880;    // 1,048,576
  const i64 oKVR     = 170131456;    // ushort [32,128,480] 3,932,160
  const i64 oVT      = 174063616;    // ushort [32,128,128] 1,048,576
  const i64 oKvrB    = 175112192;    // 4,096
  const i64 oEmomean = 175116288;    // 131,072
  const i64 oColPart = 175247360;    // float [32,64,1024] 8,388,608
  const i64 oDotE    = 183635968;    // 131,072
  const i64 oApool   = 183767040;    // 16,384
  const i64 oRoute   = 183783424;    // 131,072
  const i64 oRb      = 183914496;    // 256
  const i64 oPpart   = 183914752;    // 393,216
  const i64 oGate    = 184307968;    // 512

  unsigned short* emoB    = (unsigned short*)(ws + oEmoB);
  unsigned short* combine = (unsigned short*)(ws + oCombine);
  unsigned short* PL      = (unsigned short*)(ws + oPL);
  unsigned short* P       = PL;   // in-place softmax
  unsigned short* pooled  = (unsigned short*)(ws + oPooled);
  float*          logitsA = (float*)(ws + oLogitsA);
  float*          aggF    = (float*)(ws + oAggF);
  float*          O       = (float*)(ws + oO);
  unsigned short* CT      = (unsigned short*)(ws + oCT);
  unsigned short* Q       = (unsigned short*)(ws + oQ);
  unsigned short* attnAT  = (unsigned short*)(ws + oAttnAT);
  unsigned short* aggB    = (unsigned short*)(ws + oAggB);
  unsigned short* wvT     = (unsigned short*)(ws + oWvT);
  unsigned short* aaT     = (unsigned short*)(ws + oAaT);
  unsigned short* acT     = (unsigned short*)(ws + oAcT);
  unsigned short* wqT     = (unsigned short*)(ws + oWqT);
  unsigned short* kvrT    = (unsigned short*)(ws + oKvrT);
  unsigned short* KVR     = (unsigned short*)(ws + oKVR);
  unsigned short* VT      = (unsigned short*)(ws + oVT);
  float*          kvrB    = (float*)(ws + oKvrB);
  float*          emomean = (float*)(ws + oEmomean);
  float*          colPart = (float*)(ws + oColPart);
  float*          dotE    = (float*)(ws + oDotE);
  float*          Apool   = (float*)(ws + oApool);
  float*          route   = (float*)(ws + oRoute);
  float*          rbv     = (float*)(ws + oRb);
  float*          Ppart   = (float*)(ws + oPpart);
  float*          gate    = (float*)(ws + oGate);

  dim3 blk(256);

  // fused emo pass: colPart + dotE + emoB (2048 blocks)
  emo_pass1<<<dim3(64, 32), blk, 0, stream>>>(emo, ele_W, emoB, colPart, dotE);

  // weight prep (single launch) + bias pack
  transpose_all<<<dim3(101, 32), blk, 0, stream>>>(w_v_W, agg_a_W, agg_c_W, wq_W, wk_W, wv_W, wr_W,
                                                   wvT, aaT, acT, wqT, kvrT);
  kvr_bias_kernel<<<2, blk, 0, stream>>>(wk_b, wv_b, wr_b, kvrB);

  // feature aggregation
  pool_phr<<<8192, blk, 0, stream>>>(phr, pooled);
  vconv<<<8192, blk, 0, stream>>>(video, combine);
  gemm_mfma<1, 1, 0, 1><<<dim3(8, 2, 32), blk, 0, stream>>>(pooled, 262144, wvT, 0, w_v_b,
      (void*)combine, 524288, nullptr, 0, 1024, 1024, 1024, 1024, 1024, nullptr, 0, nullptr);
  gemm_mfma<1, 0, 0, 1><<<dim3(1, 4, 32), blk, 0, stream>>>(combine, 524288, aaT, 0, agg_a_b,
      (void*)logitsA, 65536, nullptr, 0, 128, 1024, 1024, 1024, 128, nullptr, 0, nullptr);
  softmax_attn_a<<<4096, blk, 0, stream>>>(logitsA, attnAT);
  gemm_mfma<2, 1, 0, 1><<<dim3(4, 8, 32), blk, 0, stream>>>(acT, 0, combine, 524288, agg_c_b,
      (void*)CT, 524288, nullptr, 0, 512, 1024, 1024, 1024, 512, nullptr, 0, nullptr);
  gemm_mfma<0, 2, 0, 1><<<dim3(8, 1, 32), blk, 0, stream>>>(attnAT, 65536, CT, 524288, nullptr,
      (void*)aggF, 131072, aggB, 131072, 1024, 512, 512, 512, 1024, nullptr, 0, nullptr);

  // element routing (fp32)
  colmean2<<<dim3(4, 32), blk, 0, stream>>>(colPart, emomean);
  apool_kernel<<<1024, blk, 0, stream>>>(emomean, aggF, Apool);
  route_kernel<<<dim3(4, 32), blk, 0, stream>>>(Apool, aggF, route);
  rb_kernel<<<32, blk, 0, stream>>>(route, ele_W, ele_b, rbv);

  // KVR = agg @ [wk|wv|wr] + bias
  gemm_mfma<1, 1, 0, 1><<<dim3(4, 1, 32), blk, 0, stream>>>(aggB, 131072, kvrT, 0, kvrB,
      (void*)KVR, 61440, nullptr, 0, 480, 1024, 1024, 1024, 480, nullptr, 0, nullptr);
  vt_fill<<<dim3(64, 32), blk, 0, stream>>>(KVR, VT);
  // G6: Q = tanh(dotE+rb) * (emoB @ wq) + b  (row-scale epilogue)
  gemm_mfma<1, 1, 1, 1><<<dim3(4, 8, 32), blk, 0, stream>>>(emoB, 1048576, wqT, 0, wq_b,
      (void*)Q, 458752, nullptr, 0, 448, 1024, 1024, 1024, 448, dotE, 1024, rbv);

  // G8 (fused, z=96): PL[b,i] = Q_blk @ K_blk^T (bf16 logits)
  gemm_mfma<0, 1, 0, 1, 1><<<dim3(1, 8, 96), blk, 0, stream>>>(Q, 458752, KVR, 61440, nullptr,
      (void*)PL, 131072, nullptr, 0, 128, 0, 448, 480, 128, nullptr, 0, nullptr);

  softmax_P_bf<<<24576, blk, 0, stream>>>(PL, P);
  pmean1_kernel<<<dim3(96, 8), 128, 0, stream>>>(P, Ppart);
  // OV: O = tanh((P @ VT^T)/3)
  gemm_mfma<0, 3, 0, 3><<<dim3(1, 8, 96), blk, 0, stream>>>(P, 131072, VT, 16384, nullptr,
      (void*)O, 28672, nullptr, 0, 28, 128, 128, 128, 28, nullptr, 0, nullptr);
  pmean2_rdiag<<<32, 128, 0, stream>>>(Ppart, KVR, gate);
  final_kernel<<<32768, blk, 0, stream>>>(emoB, dotE, rbv, O, gate, (float*)d_out);
}

// Round 7
// 453.894 us; speedup vs baseline: 1.0143x; 1.0143x over previous
//
#include <hip/hip_runtime.h>
#include <math.h>

typedef long long i64;
typedef __attribute__((ext_vector_type(8))) short bf16x8;
typedef __attribute__((ext_vector_type(4))) float f32x4;

#define TEMP_ISQ 0.047245559f   // 1/sqrt(448)

__device__ __forceinline__ unsigned short f2b(float x) {
  union { float f; unsigned u; } a; a.f = x;
  return (unsigned short)((a.u + 0x7fffu + ((a.u >> 16) & 1u)) >> 16);
}
__device__ __forceinline__ float b2f(unsigned short b) {
  union { float f; unsigned u; } a; a.u = ((unsigned)b) << 16; return a.f;
}

// ================= NT bf16 MFMA GEMM =================
// out[M,N] = A[M,K] @ BT[N,K]^T (+bias). 128x128 tile, BK=32 double-buffered,
// ONE barrier per K-step (prefetch next tile before compute). T1 chunked XCD
// swizzle (requires nwg % 8 == 0). LDS slot XOR f(r)=(r>>1)&3 on BOTH the
// staged global source and the ds_read (rule #21) -- round-3-proven, 2-way max.
// BIAS: 0 none, 1 col bias[col], 2 row bias[row]
// OUTM: 0 fp32, 1 bf16, 2 both (fp32 Ob + bf16 O2b), 3 fp32 tanh(acc/3)
// RS:   1 -> v *= tanhf(rowScale[zA*sRS + row] + rsAdd[zA])
// BZDIV: B batch index = z / BZDIV (XMODE 0 only)
// XMODE: 0 normal; 2 PL mode (zA=z/3: A per zA, B per z, col-bias per z);
//        3 W2T mode (z->(b,i): A=KVR+b*sA+doff_i ld 480, B=wqB+doff_i, Kd=d_i)
template<int BIAS, int OUTM, int RS, int BZDIV, int XMODE = 0>
__global__ __launch_bounds__(256)
void gemm_mfma(const unsigned short* __restrict__ Ab, i64 sA,
               const unsigned short* __restrict__ Bb, i64 sB,
               const float* __restrict__ bias,
               void* __restrict__ Ob, i64 sO,
               unsigned short* __restrict__ O2b, i64 sO2,
               int Nn, int Kd, int ldA, int ldB, int ldO,
               const float* __restrict__ rowScale, i64 sRS,
               const float* __restrict__ rsAdd)
{
  __shared__ unsigned short As[2][4096];   // 2 x (128 rows x 32 cols) bf16
  __shared__ unsigned short Bs[2][4096];
  const int tid = threadIdx.x;
  const int w = tid >> 6, lane = tid & 63;

  // T1 chunked XCD swizzle
  const int gx = gridDim.x, gy = gridDim.y;
  int nwg = gx * gy * gridDim.z;
  int bid = blockIdx.x + gx * (blockIdx.y + gy * blockIdx.z);
  int L = bid;
  if ((nwg & 7) == 0) L = (bid & 7) * (nwg >> 3) + (bid >> 3);
  const int bx = L % gx;
  int rem = L / gx;
  const int by = rem % gy;
  const int z  = rem / gy;

  const int m0 = by * 128, n0 = bx * 128;
  int zA = (XMODE == 2) ? z / 3 : z;
  const unsigned short* A;
  const unsigned short* B;
  int KdL = Kd;
  if (XMODE == 3) {
    int bb = z / 3, ii = z - bb * 3;
    const int dof_[3] = {0, 256, 384};
    const int kdt_[3] = {256, 128, 64};
    A = Ab + (i64)bb * sA + dof_[ii];
    B = Bb + dof_[ii];
    KdL = kdt_[ii];
  } else if (XMODE == 2) {
    A = Ab + (i64)zA * sA;
    B = Bb + (i64)z * sB;
  } else {
    A = Ab + (i64)z * sA;
    B = Bb + (i64)(BZDIV == 1 ? z : z / BZDIV) * sB;
  }
  const int wr = w >> 1, wc = w & 1;
  const int rS = tid >> 2, sS = tid & 3;       // stage: row (0..63), slot (0..3)
  const int cL = lane & 15, sl = lane >> 4;

  f32x4 acc[4][4];
  #pragma unroll
  for (int i = 0; i < 4; ++i)
    #pragma unroll
    for (int j = 0; j < 4; ++j) acc[i][j] = (f32x4){0.f, 0.f, 0.f, 0.f};

  // stage one 128x32 K-tile; LDS dest linear, source slot pre-XOR'd (rule #21)
  auto STAGE = [&](int buf, int k0) {
    #pragma unroll
    for (int q = 0; q < 2; ++q) {
      int r = rS + q * 64;
      int sg = sS ^ ((r >> 1) & 3);
      const unsigned short* sa = A + (i64)(m0 + r) * ldA + k0 + sg * 8;
      const unsigned short* sb = B + (i64)(n0 + r) * ldB + k0 + sg * 8;
      __builtin_amdgcn_global_load_lds(
          (__attribute__((address_space(1))) void*)sa,
          (__attribute__((address_space(3))) void*)&As[buf][r * 32 + sS * 8], 16, 0, 0);
      __builtin_amdgcn_global_load_lds(
          (__attribute__((address_space(1))) void*)sb,
          (__attribute__((address_space(3))) void*)&Bs[buf][r * 32 + sS * 8], 16, 0, 0);
    }
  };

  STAGE(0, 0);
  __syncthreads();

  for (int k0 = 0; k0 < KdL; k0 += 32) {
    const int cur = (k0 >> 5) & 1;
    if (k0 + 32 < KdL) STAGE(cur ^ 1, k0 + 32);   // prefetch flies under compute
    bf16x8 af[4], bfv[4];
    #pragma unroll
    for (int mi = 0; mi < 4; ++mi) {
      int rr = wr * 64 + mi * 16 + cL;
      int ph = sl ^ ((rr >> 1) & 3);
      af[mi] = *(const bf16x8*)&As[cur][rr * 32 + ph * 8];
    }
    #pragma unroll
    for (int ni = 0; ni < 4; ++ni) {
      int rr = wc * 64 + ni * 16 + cL;
      int ph = sl ^ ((rr >> 1) & 3);
      bfv[ni] = *(const bf16x8*)&Bs[cur][rr * 32 + ph * 8];
    }
    #pragma unroll
    for (int mi = 0; mi < 4; ++mi)
      #pragma unroll
      for (int ni = 0; ni < 4; ++ni)
        acc[mi][ni] = __builtin_amdgcn_mfma_f32_16x16x32_bf16(af[mi], bfv[ni], acc[mi][ni], 0, 0, 0);
    __syncthreads();
  }

  // D layout: col=lane&15, row=(lane>>4)*4+reg
  const float* bp = (XMODE == 2) ? (bias + (i64)z * 128) : bias;
  #pragma unroll
  for (int mi = 0; mi < 4; ++mi) {
    const int rowb = m0 + wr * 64 + mi * 16 + sl * 4;
    #pragma unroll
    for (int ni = 0; ni < 4; ++ni) {
      const int col = n0 + wc * 64 + ni * 16 + cL;
      if (col < Nn) {
        float bc = (BIAS == 1) ? bp[col] : 0.f;
        #pragma unroll
        for (int rg = 0; rg < 4; ++rg) {
          float v = acc[mi][ni][rg];
          if (RS) v *= tanhf(rowScale[(i64)zA * sRS + rowb + rg] + rsAdd[zA]);
          v += bc;
          if (BIAS == 2) v += bias[rowb + rg];
          i64 oidx = (i64)(rowb + rg) * ldO + col;
          if (OUTM == 0)      ((float*)Ob)[(i64)z * sO + oidx] = v;
          else if (OUTM == 1) ((unsigned short*)Ob)[(i64)z * sO + oidx] = f2b(v);
          else if (OUTM == 3) ((float*)Ob)[(i64)z * sO + oidx] = tanhf(v * (1.f / 3.f));
          else {
            ((float*)Ob)[(i64)z * sO + oidx] = v;
            O2b[(i64)z * sO2 + oidx] = f2b(v);
          }
        }
      }
    }
  }
}

// ================= fused emo pass =================
// 2048 blocks (16 rows each): colPart [32][64][1024], dotE, emoB
__global__ __launch_bounds__(256)
void emo_pass1(const float* __restrict__ emo, const float* __restrict__ eleW,
               unsigned short* __restrict__ emoB, float* __restrict__ colPart,
               float* __restrict__ dotE) {
  int b = blockIdx.y, lc = blockIdx.x;   // 64 chunks x 16 rows
  int t = threadIdx.x, lane = t & 63, w = t >> 6;
  float4 w4 = ((const float4*)eleW)[t];
  float4 acc = make_float4(0.f, 0.f, 0.f, 0.f);
  __shared__ float dw[16][4];
  const float4* src = (const float4*)emo + ((i64)b * 1024 + lc * 16) * 256;
  ushort4* dst = (ushort4*)emoB + ((i64)b * 1024 + lc * 16) * 256;
  #pragma unroll 4
  for (int lr = 0; lr < 16; ++lr) {
    float4 v = src[lr * 256 + t];
    acc.x += v.x; acc.y += v.y; acc.z += v.z; acc.w += v.w;
    float d = v.x * w4.x + v.y * w4.y + v.z * w4.z + v.w * w4.w;
    #pragma unroll
    for (int o = 32; o; o >>= 1) d += __shfl_xor(d, o);
    if (!lane) dw[lr][w] = d;
    ushort4 o4; o4.x = f2b(v.x); o4.y = f2b(v.y); o4.z = f2b(v.z); o4.w = f2b(v.w);
    dst[lr * 256 + t] = o4;
  }
  __syncthreads();
  if (t < 16) dotE[(i64)b * 1024 + lc * 16 + t] = dw[t][0] + dw[t][1] + dw[t][2] + dw[t][3];
  ((float4*)colPart)[((i64)b * 64 + lc) * 256 + t] = acc;
}

__global__ void colmean2(const float* __restrict__ colPart, float* __restrict__ emomean) {
  int b = blockIdx.y, e = blockIdx.x * 256 + threadIdx.x;
  float s = 0.f;
  #pragma unroll 8
  for (int lc = 0; lc < 64; ++lc) s += colPart[((i64)b * 64 + lc) * 1024 + e];
  emomean[b * 1024 + e] = s * (1.f / 1024.f);
}

// ================= prep kernels =================
// 6 weight transposes + wq bf16 convert, one launch. grid (98, 32).
__global__ __launch_bounds__(256)
void transpose_all(const float* __restrict__ w_v_W, const float* __restrict__ agg_a_W,
                   const float* __restrict__ agg_c_W, const float* __restrict__ wq_W,
                   const float* __restrict__ wk_W, const float* __restrict__ wv_W,
                   const float* __restrict__ wr_W,
                   unsigned short* __restrict__ wvT, unsigned short* __restrict__ aaT,
                   unsigned short* __restrict__ acT, unsigned short* __restrict__ wqB,
                   unsigned short* __restrict__ kvrT) {
  int bx = blockIdx.x;
  int t = threadIdx.x;
  if (bx >= 84) {   // wqB: plain fp32->bf16 convert of wq_W [1024x448]
    i64 li = (((i64)(bx - 84) * 32 + blockIdx.y) * 256 + t) * 4;
    float4 v = *(const float4*)(wq_W + li);
    ushort4 o; o.x = f2b(v.x); o.y = f2b(v.y); o.z = f2b(v.z); o.w = f2b(v.w);
    *(ushort4*)(wqB + li) = o;
    return;
  }
  __shared__ float T[32][33];
  const float* in; unsigned short* out; int N, Npad, s0;
  if (bx < 32)      { in = w_v_W;   out = wvT;                     N = 1024; Npad = 1024; s0 = 0; }
  else if (bx < 36) { in = agg_a_W; out = aaT;                     N = 128;  Npad = 128;  s0 = 32; }
  else if (bx < 68) { in = agg_c_W; out = acT;                     N = 1024; Npad = 1024; s0 = 36; }
  else if (bx < 82) { in = wk_W;    out = kvrT;                    N = 448;  Npad = 448;  s0 = 68; }
  else if (bx < 83) { in = wv_W;    out = kvrT + (i64)448 * 1024;  N = 28;   Npad = 28;   s0 = 82; }
  else              { in = wr_W;    out = kvrT + (i64)476 * 1024;  N = 3;    Npad = 36;   s0 = 83; }
  int n0 = (bx - s0) * 32, k0 = blockIdx.y * 32;
  #pragma unroll
  for (int p = 0; p < 4; ++p) {
    int idx = t + 256 * p; int kk = idx >> 5, nn = idx & 31;
    float v = 0.f;
    if (n0 + nn < N) v = in[(i64)(k0 + kk) * N + (n0 + nn)];
    T[nn][kk] = v;
  }
  __syncthreads();
  #pragma unroll
  for (int p = 0; p < 4; ++p) {
    int idx = t + 256 * p; int nn = idx >> 5, kk = idx & 31;
    if (n0 + nn < Npad) out[(i64)(n0 + nn) * 1024 + (k0 + kk)] = f2b(T[nn][kk]);
  }
}

__global__ void kvr_bias_kernel(const float* wkb, const float* wvb, const float* wrb, float* out) {
  int t = blockIdx.x * 256 + threadIdx.x;
  if (t >= 480) return;
  out[t] = (t < 448) ? wkb[t] : (t < 476) ? wvb[t - 448] : (t < 479) ? wrb[t - 476] : 0.f;
}

// qb[z=(b,i)][k] = sum_d K_i[b,k,d] * wq_b[doff_i+d]
__global__ void qb_kernel(const unsigned short* __restrict__ KVR, const float* __restrict__ wq_b,
                          float* __restrict__ qb) {
  int zz = blockIdx.x;   // 96
  int bb = zz / 3, ii = zz - bb * 3;
  const int dof_[3] = {0, 256, 384};
  const int kdt_[3] = {256, 128, 64};
  int k = threadIdx.x;   // 128
  const unsigned short* kp = KVR + (i64)bb * 61440 + k * 480 + dof_[ii];
  const float* wb = wq_b + dof_[ii];
  float s = 0.f;
  for (int d = 0; d < kdt_[ii]; ++d) s += b2f(kp[d]) * wb[d];
  qb[zz * 128 + k] = s;
}

__global__ void pool_phr(const float* __restrict__ phr, unsigned short* __restrict__ out) {
  i64 idx = (i64)blockIdx.x * 256 + threadIdx.x;
  if (idx >= 2097152) return;
  i64 bm = idx >> 8; int c = (int)(idx & 255);
  i64 b = bm >> 8, m = bm & 255;
  const float4* r0 = (const float4*)(phr + (b * 512 + 2 * m) * 1024) + c;
  const float4* r1 = (const float4*)(phr + (b * 512 + 2 * m + 1) * 1024) + c;
  float4 a = *r0, d = *r1;
  ushort4 o;
  o.x = f2b(0.5f * (a.x + d.x)); o.y = f2b(0.5f * (a.y + d.y));
  o.z = f2b(0.5f * (a.z + d.z)); o.w = f2b(0.5f * (a.w + d.w));
  ((ushort4*)out)[idx] = o;
}

__global__ void vconv(const float* __restrict__ video, unsigned short* __restrict__ combine) {
  i64 idx = (i64)blockIdx.x * 256 + threadIdx.x;
  if (idx >= 2097152) return;
  i64 b = idx >> 16, r = idx & 65535;
  float4 v = ((const float4*)video)[idx];
  ushort4 o;
  o.x = f2b(v.x); o.y = f2b(v.y); o.z = f2b(v.z); o.w = f2b(v.w);
  ((ushort4*)combine)[b * 131072 + 65536 + r] = o;
}

// VT[b][n][k] = KVR[b][k][448+n] (n<28), 0 pad to 128 rows
__global__ void vt_fill(const unsigned short* __restrict__ KVR, unsigned short* __restrict__ VT) {
  int b = blockIdx.y;
  int idx = blockIdx.x * 256 + threadIdx.x;
  int n = idx >> 7, k = idx & 127;
  unsigned short v = 0;
  if (n < 28) v = KVR[(i64)b * 61440 + k * 480 + 448 + n];
  VT[((i64)b * 128 + n) * 128 + k] = v;
}

// ================= softmax / routing =================
__global__ void softmax_attn_a(const float* __restrict__ logits, unsigned short* __restrict__ outT) {
  int gw = (int)(((i64)blockIdx.x * blockDim.x + threadIdx.x) >> 6);
  int lane = threadIdx.x & 63;
  if (gw >= 32 * 512) return;
  int b = gw >> 9, m = gw & 511;
  const float* p = logits + (i64)gw * 128;
  float x0 = p[lane], x1 = p[lane + 64];
  float mx = fmaxf(x0, x1);
  #pragma unroll
  for (int o = 32; o; o >>= 1) mx = fmaxf(mx, __shfl_xor(mx, o));
  float e0 = expf(x0 - mx), e1 = expf(x1 - mx);
  float s = e0 + e1;
  #pragma unroll
  for (int o = 32; o; o >>= 1) s += __shfl_xor(s, o);
  float inv = 1.f / s;
  unsigned short* o0 = outT + (i64)b * 128 * 512 + m;
  o0[(i64)lane * 512] = f2b(e0 * inv);
  o0[(i64)(lane + 64) * 512] = f2b(e1 * inv);
}

// in-place: each warp owns one row of PL; reads fully before writing
__global__ void softmax_P_bf(const unsigned short* __restrict__ PL, unsigned short* __restrict__ P) {
  i64 gw = ((i64)blockIdx.x * blockDim.x + threadIdx.x) >> 6;
  int lane = threadIdx.x & 63;
  if (gw >= 98304) return;
  const unsigned short* p = PL + gw * 128;
  float x0 = b2f(p[lane]) * TEMP_ISQ, x1 = b2f(p[lane + 64]) * TEMP_ISQ;
  float mx = fmaxf(x0, x1);
  #pragma unroll
  for (int o = 32; o; o >>= 1) mx = fmaxf(mx, __shfl_xor(mx, o));
  float e0 = expf(x0 - mx), e1 = expf(x1 - mx);
  float s = e0 + e1;
  #pragma unroll
  for (int o = 32; o; o >>= 1) s += __shfl_xor(s, o);
  float inv = 1.f / s;
  P[gw * 128 + lane] = f2b(e0 * inv);
  P[gw * 128 + lane + 64] = f2b(e1 * inv);
}

__global__ void apool_kernel(const float* __restrict__ emomean, const float* __restrict__ agg,
                             float* __restrict__ Apool) {
  int gw = (int)(((i64)blockIdx.x * blockDim.x + threadIdx.x) >> 6);
  int lane = threadIdx.x & 63;
  if (gw >= 32 * 128) return;
  int b = gw >> 7, k = gw & 127;
  const float* ag = agg + ((i64)b * 128 + k) * 1024;
  const float* em = emomean + (i64)b * 1024;
  float s = 0.f;
  #pragma unroll
  for (int j = 0; j < 16; ++j) { int e = j * 64 + lane; s += em[e] * ag[e]; }
  #pragma unroll
  for (int o = 32; o; o >>= 1) s += __shfl_down(s, o);
  if (!lane) Apool[gw] = s;
}

// route[b,e] = sum_k Apool[b,k]*agg[b,k,e]  (grid (4,32))
__global__ void route_kernel(const float* __restrict__ Apool, const float* __restrict__ agg,
                             float* __restrict__ route) {
  int b = blockIdx.y;
  int e = blockIdx.x * 256 + threadIdx.x;
  __shared__ float Ap[128];
  if (threadIdx.x < 128) Ap[threadIdx.x] = Apool[b * 128 + threadIdx.x];
  __syncthreads();
  const float* ag = agg + (i64)b * 128 * 1024 + e;
  float s = 0.f;
  #pragma unroll 8
  for (int k = 0; k < 128; ++k) s += Ap[k] * ag[(i64)k * 1024];
  route[b * 1024 + e] = s;
}

__global__ void rb_kernel(const float* __restrict__ route, const float* __restrict__ eleW,
                          const float* __restrict__ eleb, float* __restrict__ rb) {
  int b = blockIdx.x, t = threadIdx.x;
  float s = 0.f;
  for (int j = t; j < 1024; j += 256) s += route[b * 1024 + j] * eleW[1024 + j];
  __shared__ float red[256];
  red[t] = s; __syncthreads();
  for (int o = 128; o > 0; o >>= 1) { if (t < o) red[t] += red[t + o]; __syncthreads(); }
  if (t == 0) rb[b] = red[0] + eleb[0];
}

// ================= P consumers =================
__global__ void pmean1_kernel(const unsigned short* __restrict__ P, float* __restrict__ Ppart) {
  int bi = blockIdx.x, c = blockIdx.y, k = threadIdx.x;
  const unsigned short* p = P + ((i64)bi * 1024 + c * 128) * 128 + k;
  float s = 0.f;
  for (int l = 0; l < 128; ++l) s += b2f(p[(i64)l * 128]);
  Ppart[((i64)bi * 8 + c) * 128 + k] = s;
}

// fused pmean2 + rdiag + gate (32 blocks x 128 threads)
__global__ void pmean2_rdiag(const float* __restrict__ Ppart, const unsigned short* __restrict__ KVR,
                             float* __restrict__ gate) {
  int b = blockIdx.x, t = threadIdx.x;
  __shared__ float red[128];
  __shared__ float rd[3];
  for (int i = 0; i < 3; ++i) {
    float s = 0.f;
    #pragma unroll
    for (int c = 0; c < 8; ++c) s += Ppart[((i64)(b * 3 + i) * 8 + c) * 128 + t];
    float v = s * (1.f / 1024.f) * b2f(KVR[(i64)b * 61440 + t * 480 + 476 + i]);
    red[t] = v; __syncthreads();
    for (int o = 64; o > 0; o >>= 1) { if (t < o) red[t] += red[t + o]; __syncthreads(); }
    if (t == 0) rd[i] = red[0];
    __syncthreads();
  }
  if (t == 0) {
    float m = fmaxf(rd[0], fmaxf(rd[1], rd[2]));
    float e0 = expf(rd[0] - m), e1 = expf(rd[1] - m), e2 = expf(rd[2] - m);
    float inv = 1.f / (e0 + e1 + e2);
    gate[b * 3 + 0] = e0 * inv; gate[b * 3 + 1] = e1 * inv; gate[b * 3 + 2] = e2 * inv;
  }
}

// out = b2f(emoB) * (1 + tanh(dotE+rb) * sum_i gate_i * O_i)
__global__ __launch_bounds__(256)
void final_kernel(const unsigned short* __restrict__ emoB, const float* __restrict__ dotE,
                  const float* __restrict__ rbv, const float* __restrict__ O,
                  const float* __restrict__ gate, float* __restrict__ out) {
  i64 bl = blockIdx.x;
  int b = (int)(bl >> 10), l = (int)(bl & 1023);
  __shared__ float Gg[16];
  int t = threadIdx.x;
  if (t < 16) {
    float g0 = gate[b * 3], g1 = gate[b * 3 + 1], g2 = gate[b * 3 + 2];
    float o0 = O[((i64)(b * 3 + 0) * 1024 + l) * 28 + (t >> 2)];
    float o1 = O[((i64)(b * 3 + 1) * 1024 + l) * 28 + 4 + (t >> 1)];
    float o2 = O[((i64)(b * 3 + 2) * 1024 + l) * 28 + 12 + t];
    Gg[t] = g0 * o0 + g1 * o1 + g2 * o2;
  }
  __syncthreads();
  float re = tanhf(dotE[bl] + rbv[b]);
  ushort4 e4 = ((const ushort4*)(emoB + bl * 1024))[t];
  float g = 1.f + re * Gg[t >> 4];
  ((float4*)(out + bl * 1024))[t] =
      make_float4(b2f(e4.x) * g, b2f(e4.y) * g, b2f(e4.z) * g, b2f(e4.w) * g);
}

// ================= launcher =================
extern "C" void kernel_launch(void* const* d_in, const int* in_sizes, int n_in,
                              void* d_out, int out_size, void* d_ws, size_t ws_size,
                              hipStream_t stream) {
  const float* emo     = (const float*)d_in[0];
  const float* phr     = (const float*)d_in[1];
  const float* video   = (const float*)d_in[2];
  const float* w_v_W   = (const float*)d_in[3];
  const float* w_v_b   = (const float*)d_in[4];
  const float* agg_a_W = (const float*)d_in[5];
  const float* agg_a_b = (const float*)d_in[6];
  const float* agg_c_W = (const float*)d_in[7];
  const float* agg_c_b = (const float*)d_in[8];
  const float* ele_W   = (const float*)d_in[9];
  const float* ele_b   = (const float*)d_in[10];
  const float* wq_W    = (const float*)d_in[11];
  const float* wq_b    = (const float*)d_in[12];
  const float* wk_W    = (const float*)d_in[13];
  const float* wk_b    = (const float*)d_in[14];
  const float* wv_W    = (const float*)d_in[15];
  const float* wv_b    = (const float*)d_in[16];
  const float* wr_W    = (const float*)d_in[17];
  const float* wr_b    = (const float*)d_in[18];

  char* ws = (char*)d_ws;
  // ---- region map (bytes) ----
  const i64 oEmoB    = 0;            // ushort [32,1024,1024] 67,108,864 (live to the end)
  const i64 oCombine = 67108864;     // ushort [32,512,1024] (dead after G3')
  const i64 oPL      = 67108864;     //   overlay: ushort [96,1024,128]; softmax IN-PLACE -> P
  const i64 oPooled  = 100663296;    // ushort [32,256,1024] (dead after G1)
  const i64 oLogitsA = 100663296;    //   overlay: float [32,512,128] (dead after softmax_attn_a)
  const i64 oAggF    = 100663296;    //   overlay: float [32,128,1024] (dead after route)
  const i64 oO       = 100663296;    //   overlay: float [96,1024,28] (written after route)
  const i64 oCT      = 117440512;    // ushort [32,1024,512] (dead after G4)
  const i64 oW2T     = 117440512;    //   overlay: ushort [96,128,1024] 25,165,824 (after KVR)
  const i64 oAttnAT  = 150994944;    // ushort [32,128,512] 4,194,304
  const i64 oAggB    = 155189248;    // ushort [32,128,1024] 8,388,608
  const i64 oWvT     = 163577856;    // 2,097,152
  const i64 oAaT     = 165675008;    // 262,144
  const i64 oAcT     = 165937152;    // 2,097,152
  const i64 oWqB     = 168034304;    // ushort [1024,448] 917,504 (in 1,048,576 slot)
  const i64 oKvrT    = 169082880;    // 1,048,576
  const i64 oKVR     = 170131456;    // ushort [32,128,480] 3,932,160
  const i64 oVT      = 174063616;    // ushort [32,128,128] 1,048,576
  const i64 oKvrB    = 175112192;    // 4,096
  const i64 oEmomean = 175116288;    // 131,072
  const i64 oColPart = 175247360;    // float [32,64,1024] 8,388,608
  const i64 oDotE    = 183635968;    // 131,072
  const i64 oApool   = 183767040;    // 16,384
  const i64 oRoute   = 183783424;    // 131,072 (dead after rb) -> qb overlay [96,128] f32
  const i64 oRb      = 183914496;    // 256
  const i64 oPpart   = 183914752;    // 393,216
  const i64 oGate    = 184307968;    // 512

  unsigned short* emoB    = (unsigned short*)(ws + oEmoB);
  unsigned short* combine = (unsigned short*)(ws + oCombine);
  unsigned short* PL      = (unsigned short*)(ws + oPL);
  unsigned short* P       = PL;   // in-place softmax
  unsigned short* pooled  = (unsigned short*)(ws + oPooled);
  float*          logitsA = (float*)(ws + oLogitsA);
  float*          aggF    = (float*)(ws + oAggF);
  float*          O       = (float*)(ws + oO);
  unsigned short* CT      = (unsigned short*)(ws + oCT);
  unsigned short* W2T     = (unsigned short*)(ws + oW2T);
  unsigned short* attnAT  = (unsigned short*)(ws + oAttnAT);
  unsigned short* aggB    = (unsigned short*)(ws + oAggB);
  unsigned short* wvT     = (unsigned short*)(ws + oWvT);
  unsigned short* aaT     = (unsigned short*)(ws + oAaT);
  unsigned short* acT     = (unsigned short*)(ws + oAcT);
  unsigned short* wqB     = (unsigned short*)(ws + oWqB);
  unsigned short* kvrT    = (unsigned short*)(ws + oKvrT);
  unsigned short* KVR     = (unsigned short*)(ws + oKVR);
  unsigned short* VT      = (unsigned short*)(ws + oVT);
  float*          kvrB    = (float*)(ws + oKvrB);
  float*          emomean = (float*)(ws + oEmomean);
  float*          colPart = (float*)(ws + oColPart);
  float*          dotE    = (float*)(ws + oDotE);
  float*          Apool   = (float*)(ws + oApool);
  float*          route   = (float*)(ws + oRoute);
  float*          qb      = (float*)(ws + oRoute);   // overlay after rb_kernel
  float*          rbv     = (float*)(ws + oRb);
  float*          Ppart   = (float*)(ws + oPpart);
  float*          gate    = (float*)(ws + oGate);

  dim3 blk(256);

  // fused emo pass: colPart + dotE + emoB (2048 blocks)
  emo_pass1<<<dim3(64, 32), blk, 0, stream>>>(emo, ele_W, emoB, colPart, dotE);

  // weight prep (single launch) + bias pack
  transpose_all<<<dim3(98, 32), blk, 0, stream>>>(w_v_W, agg_a_W, agg_c_W, wq_W, wk_W, wv_W, wr_W,
                                                  wvT, aaT, acT, wqB, kvrT);
  kvr_bias_kernel<<<2, blk, 0, stream>>>(wk_b, wv_b, wr_b, kvrB);

  // feature aggregation
  pool_phr<<<8192, blk, 0, stream>>>(phr, pooled);
  vconv<<<8192, blk, 0, stream>>>(video, combine);
  gemm_mfma<1, 1, 0, 1><<<dim3(8, 2, 32), blk, 0, stream>>>(pooled, 262144, wvT, 0, w_v_b,
      (void*)combine, 524288, nullptr, 0, 1024, 1024, 1024, 1024, 1024, nullptr, 0, nullptr);
  gemm_mfma<1, 0, 0, 1><<<dim3(1, 4, 32), blk, 0, stream>>>(combine, 524288, aaT, 0, agg_a_b,
      (void*)logitsA, 65536, nullptr, 0, 128, 1024, 1024, 1024, 128, nullptr, 0, nullptr);
  softmax_attn_a<<<4096, blk, 0, stream>>>(logitsA, attnAT);
  gemm_mfma<2, 1, 0, 1><<<dim3(4, 8, 32), blk, 0, stream>>>(acT, 0, combine, 524288, agg_c_b,
      (void*)CT, 524288, nullptr, 0, 512, 1024, 1024, 1024, 512, nullptr, 0, nullptr);
  gemm_mfma<0, 2, 0, 1><<<dim3(8, 1, 32), blk, 0, stream>>>(attnAT, 65536, CT, 524288, nullptr,
      (void*)aggF, 131072, aggB, 131072, 1024, 512, 512, 512, 1024, nullptr, 0, nullptr);

  // element routing (fp32)
  colmean2<<<dim3(4, 32), blk, 0, stream>>>(colPart, emomean);
  apool_kernel<<<1024, blk, 0, stream>>>(emomean, aggF, Apool);
  route_kernel<<<dim3(4, 32), blk, 0, stream>>>(Apool, aggF, route);
  rb_kernel<<<32, blk, 0, stream>>>(route, ele_W, ele_b, rbv);

  // KVR = agg @ [wk|wv|wr] + bias
  gemm_mfma<1, 1, 0, 1><<<dim3(4, 1, 32), blk, 0, stream>>>(aggB, 131072, kvrT, 0, kvrB,
      (void*)KVR, 61440, nullptr, 0, 480, 1024, 1024, 1024, 480, nullptr, 0, nullptr);
  vt_fill<<<dim3(64, 32), blk, 0, stream>>>(KVR, VT);

  // W2T[z=(b,i)][k][e] = K_i[b] @ wq_i^T  (bf16)
  gemm_mfma<0, 1, 0, 1, 3><<<dim3(8, 1, 96), blk, 0, stream>>>(KVR, 61440, wqB, 0, nullptr,
      (void*)W2T, 131072, nullptr, 0, 1024, 0, 480, 448, 1024, nullptr, 0, nullptr);
  qb_kernel<<<96, 128, 0, stream>>>(KVR, wq_b, qb);

  // PL[z][l][k] = tanh(dotE+rb)_l * (emoB_l @ W2T_z) + qb_z  (bf16 logits)
  gemm_mfma<1, 1, 1, 1, 2><<<dim3(1, 8, 96), blk, 0, stream>>>(emoB, 1048576, W2T, 131072, qb,
      (void*)PL, 131072, nullptr, 0, 128, 1024, 1024, 1024, 128, dotE, 1024, rbv);

  softmax_P_bf<<<24576, blk, 0, stream>>>(PL, P);
  pmean1_kernel<<<dim3(96, 8), 128, 0, stream>>>(P, Ppart);
  // OV: O = tanh((P @ VT^T)/3)
  gemm_mfma<0, 3, 0, 3><<<dim3(1, 8, 96), blk, 0, stream>>>(P, 131072, VT, 16384, nullptr,
      (void*)O, 28672, nullptr, 0, 28, 128, 128, 128, 28, nullptr, 0, nullptr);
  pmean2_rdiag<<<32, 128, 0, stream>>>(Ppart, KVR, gate);
  final_kernel<<<32768, blk, 0, stream>>>(emoB, dotE, rbv, O, gate, (float*)d_out);
}